// Round 1
// baseline (2179.039 us; speedup 1.0000x reference)
//
#include <hip/hip_runtime.h>

// MAC network forward, restructured:
//  - inter2 GEMM (34 GMAC/step) algebraically collapsed via linearity of the
//    r_att contraction: r_att[b,k] = sum_j knowledge[b,j,k]*g[b,j],
//    g = mem_p * h[:, :D] + h[:, D:],  h = (new_control*ra_w) @ ri_w.
//  - q_pa part of control-unit GEMM hoisted out of the step loop (qc_all).
//  - ca_b / ra_b / ri_b are per-row constants under softmax -> dropped.
// All fp32.
//
// R1: gemm32 redesigned with N-register-blocking. Old mapping (1 col x 32 b
// per wave) had a 32:1 LDS:W delivered-byte ratio -> LDS-pipe bound at
// ~0.4 TB/s W stream. New mapping: 4 cols x 16 b per wave (acc[64]),
// 8 cols x 32 b per block, 32 KB X chunk (CC=256), 4 blocks/CU.
// LDS:W ratio 8:1; epilogue is a 63-shuffle butterfly reduce.

#define NSTEP 12

struct GemmArgs {
  const float* X1; long x1g;   // [32, c1], per-group stride
  const float* X2; long x2g;   // [32, c2] or null (concat second half)
  int c1, c2;
  const float* W; int ldw; long wg;      // W[N, C] row-major (out = X @ W.T)
  const float* bias; long biasg;         // len N or null
  const float* addend; long addg;        // [32, N] or null
  const float* xscale;                   // len C or null (elementwise on X)
  float* out; long outg;                 // [32, N]
  int N;
};

// out[b,n] = sum_c X[b,c]*W[n,c] (+bias +addend).
// Block: 256 thr = 4 waves, computing an 8-col x 32-row output tile.
// Wave w: columns n0 + (w>>1)*4 .. +3, batch half (w&1)*16 .. +15.
// Per chunk (256 c): stage X[32][256] in LDS; each lane owns c = lane*4..+3.
// Inner: 4 W float4 loads (global), 16 xv b128 LDS reads, 64 FMA4.
__global__ __launch_bounds__(256, 4) void gemm32_kernel(GemmArgs a) {
  __shared__ float xs[32 * 256];  // 32 KB
  const int g = blockIdx.y;
  const int C = a.c1 + a.c2;
  const float* X1 = a.X1 + (long)g * a.x1g;
  const float* X2 = a.X2 ? a.X2 + (long)g * a.x2g : nullptr;
  const float* W = a.W + (long)g * a.wg;
  const int wave = threadIdx.x >> 6;
  const int lane = threadIdx.x & 63;
  const int n0 = blockIdx.x * 8 + (wave >> 1) * 4;
  const int bh = (wave & 1) * 16;
  const float* wrow = W + (long)n0 * a.ldw;
  // acc[v], v = b_local*4 + j  (b_local in [0,16), j = column in [0,4)).
  // Butterfly reduce leaves the total for v on lane v.
  float acc[64];
#pragma unroll
  for (int v = 0; v < 64; v++) acc[v] = 0.f;

  for (int c0 = 0; c0 < C; c0 += 256) {
    __syncthreads();  // protect previous chunk's reads
#pragma unroll
    for (int r = 0; r < 8; r++) {
      int idx = threadIdx.x + 256 * r;  // 0..2047 float4 slots
      int b = idx >> 6;                 // 64 float4 per row
      int c4 = idx & 63;
      int c = c0 + c4 * 4;              // global column
      float4 v;
      if (c < a.c1) v = *(const float4*)(X1 + (long)b * a.c1 + c);
      else          v = *(const float4*)(X2 + (long)b * a.c2 + (c - a.c1));
      if (a.xscale) {
        float4 s = *(const float4*)(a.xscale + c);
        v.x *= s.x; v.y *= s.y; v.z *= s.z; v.w *= s.w;
      }
      *(float4*)(xs + b * 256 + c4 * 4) = v;
    }
    __syncthreads();
    const int c = lane * 4;
    const float* wp = wrow + c0 + c;
    float4 wv0 = *(const float4*)(wp);
    float4 wv1 = *(const float4*)(wp + (long)a.ldw);
    float4 wv2 = *(const float4*)(wp + 2 * (long)a.ldw);
    float4 wv3 = *(const float4*)(wp + 3 * (long)a.ldw);
#pragma unroll
    for (int b = 0; b < 16; b++) {
      float4 xv = *(const float4*)(xs + (bh + b) * 256 + c);
      acc[b * 4 + 0] += wv0.x * xv.x + wv0.y * xv.y + wv0.z * xv.z + wv0.w * xv.w;
      acc[b * 4 + 1] += wv1.x * xv.x + wv1.y * xv.y + wv1.z * xv.z + wv1.w * xv.w;
      acc[b * 4 + 2] += wv2.x * xv.x + wv2.y * xv.y + wv2.z * xv.z + wv2.w * xv.w;
      acc[b * 4 + 3] += wv3.x * xv.x + wv3.y * xv.y + wv3.z * xv.z + wv3.w * xv.w;
    }
  }
  // Butterfly cross-lane reduction: 63 shuffles. After stage o, lanes with
  // (lane&o)==0 hold value-indices with bit o clear (compacted into [0,o)).
  // Final: lane l holds the full sum for v = l in acc[0].
#pragma unroll
  for (int o = 32; o; o >>= 1) {
    bool up = (lane & o) != 0;
#pragma unroll
    for (int i = 0; i < o; i++) {
      float keep = up ? acc[i + o] : acc[i];
      float send = up ? acc[i] : acc[i + o];
      acc[i] = keep + __shfl_xor(send, o, 64);
    }
  }
  const int bo = bh + (lane >> 2);
  const int nn = n0 + (lane & 3);
  float res = acc[0];
  if (a.bias) res += a.bias[(long)g * a.biasg + nn];
  if (a.addend) res += a.addend[(long)g * a.addg + (long)bo * a.N + nn];
  a.out[(long)g * a.outg + (long)bo * a.N + nn] = res;
}

__global__ __launch_bounds__(1024) void init_control_kernel(const float* ci, float* control) {
  control[blockIdx.x * 1024 + threadIdx.x] = ci[0];
}

// ri_w [1024, 2048] -> ri_wT [2048, 1024]
__global__ __launch_bounds__(1024) void transpose_kernel(const float* in, float* out) {
  __shared__ float t[32][33];
  int j0 = blockIdx.x * 32;
  int d0 = blockIdx.y * 32;
  int tx = threadIdx.x, ty = threadIdx.y;
  t[ty][tx] = in[(long)(d0 + ty) * 2048 + j0 + tx];
  __syncthreads();
  out[(long)(j0 + ty) * 1024 + d0 + tx] = t[tx][ty];
}

// control-unit attention: scores over context, softmax, new_control.
// One block (1024 thr) per batch row.
__global__ __launch_bounds__(1024) void ctrl_att_kernel(const float* cq, const float* context,
                                                        const float* ca_w, float* control) {
  int b = blockIdx.x;
  __shared__ float u[1024];
  __shared__ float sc[128];
  int tid = threadIdx.x;
  int wave = tid >> 6, lane = tid & 63;
  u[tid] = cq[b * 1024 + tid] * ca_w[tid];
  __syncthreads();
  const float* ctx = context + (long)b * 128 * 1024;
#pragma unroll
  for (int i = 0; i < 8; i++) {
    int s = wave * 8 + i;  // 16 waves x 8 = 128 scores
    float v = 0.f;
#pragma unroll
    for (int c = 0; c < 16; c++) v += u[c * 64 + lane] * ctx[(long)s * 1024 + c * 64 + lane];
#pragma unroll
    for (int off = 32; off; off >>= 1) v += __shfl_xor(v, off, 64);
    if (lane == 0) sc[s] = v;  // ca_b dropped (softmax-invariant)
  }
  __syncthreads();
  if (wave == 0) {
    float a0 = sc[lane], a1 = sc[lane + 64];
    float m = fmaxf(a0, a1);
#pragma unroll
    for (int off = 32; off; off >>= 1) m = fmaxf(m, __shfl_xor(m, off, 64));
    float e0 = expf(a0 - m), e1 = expf(a1 - m);
    float s2 = e0 + e1;
#pragma unroll
    for (int off = 32; off; off >>= 1) s2 += __shfl_xor(s2, off, 64);
    float inv = 1.f / s2;
    sc[lane] = e0 * inv;
    sc[lane + 64] = e1 * inv;
  }
  __syncthreads();
  float acc = 0.f;
  for (int s = 0; s < 128; s++) acc += sc[s] * ctx[(long)s * 1024 + tid];
  control[b * 1024 + tid] = acc;
}

// r_att partials: partial[jc][b][k] = sum_{j in chunk jc} g[b,j]*knowledge[b,j,k]
__global__ __launch_bounds__(512) void ratt_kernel(const float* knowledge, const float* mem_p,
                                                   const float* h, float* partial) {
  int b = blockIdx.x, jc = blockIdx.y;
  int j0 = jc * 64;
  __shared__ float gl[64];
  if (threadIdx.x < 64) {
    int j = j0 + threadIdx.x;
    gl[threadIdx.x] = mem_p[b * 1024 + j] * h[b * 2048 + j] + h[b * 2048 + 1024 + j];
  }
  __syncthreads();
  int k = threadIdx.x;  // 512 threads <-> K=512
  const float* kb = knowledge + ((long)b * 1024 + j0) * 512 + k;
  float acc = 0.f;
#pragma unroll 8
  for (int jj = 0; jj < 64; jj++) acc += gl[jj] * kb[(long)jj * 512];
  partial[((long)jc * 32 + b) * 512 + k] = acc;
}

// softmax(r_att) + read[b,d] = sum_k a[k]*knowledge[b,d,k]
// block (b, dg): 256 thr; softmax recomputed per block from partials.
__global__ __launch_bounds__(256) void read_kernel(const float* partial, const float* knowledge,
                                                   float* readv) {
  int b = blockIdx.x, dg = blockIdx.y;
  __shared__ float aw[512];
  __shared__ float red[4];
  int tid = threadIdx.x;
  int wave = tid >> 6, lane = tid & 63;
  int k0 = tid * 2;
  float r0 = 0.f, r1 = 0.f;
#pragma unroll
  for (int p = 0; p < 16; p++) {
    const float* pp = partial + ((long)p * 32 + b) * 512;
    r0 += pp[k0];
    r1 += pp[k0 + 1];
  }
  float m = fmaxf(r0, r1);
#pragma unroll
  for (int off = 32; off; off >>= 1) m = fmaxf(m, __shfl_xor(m, off, 64));
  if (lane == 0) red[wave] = m;
  __syncthreads();
  m = fmaxf(fmaxf(red[0], red[1]), fmaxf(red[2], red[3]));
  __syncthreads();  // all reads of red done before rewrite
  float e0 = expf(r0 - m), e1 = expf(r1 - m);
  float s2 = e0 + e1;
#pragma unroll
  for (int off = 32; off; off >>= 1) s2 += __shfl_xor(s2, off, 64);
  if (lane == 0) red[wave] = s2;
  __syncthreads();
  s2 = red[0] + red[1] + red[2] + red[3];
  float inv = 1.f / s2;
  aw[k0] = e0 * inv;
  aw[k0 + 1] = e1 * inv;
  __syncthreads();
  int d0 = dg * 32 + wave * 8;  // 4 waves x 8 d each
  float acc[8];
#pragma unroll
  for (int i = 0; i < 8; i++) acc[i] = 0.f;
  const float* kb = knowledge + ((long)b * 1024 + d0) * 512;
  for (int kc = 0; kc < 8; kc++) {
    int kk = kc * 64 + lane;
    float av = aw[kk];
#pragma unroll
    for (int dd = 0; dd < 8; dd++) acc[dd] += av * kb[(long)dd * 512 + kk];
  }
#pragma unroll
  for (int dd = 0; dd < 8; dd++) {
    float v = acc[dd];
#pragma unroll
    for (int off = 32; off; off >>= 1) v += __shfl_xor(v, off, 64);
    if (lane == dd) readv[b * 1024 + d0 + dd] = v;
  }
}

static inline void launch_gemm(const float* X1, long x1g, const float* X2, long x2g,
                               int c1, int c2, const float* W, int ldw, long wg,
                               const float* bias, long biasg,
                               const float* addend, long addg,
                               const float* xscale, float* out, long outg, int N, int G,
                               hipStream_t stream) {
  GemmArgs a{X1, x1g, X2, x2g, c1, c2, W, ldw, wg, bias, biasg, addend, addg, xscale, out, outg, N};
  gemm32_kernel<<<dim3(N / 8, G), 256, 0, stream>>>(a);
}

extern "C" void kernel_launch(void* const* d_in, const int* in_sizes, int n_in,
                              void* d_out, int out_size, void* d_ws, size_t ws_size,
                              hipStream_t stream) {
  const float* context      = (const float*)d_in[0];
  const float* question     = (const float*)d_in[1];
  const float* knowledge    = (const float*)d_in[2];
  const float* control_init = (const float*)d_in[3];
  const float* pa_w = (const float*)d_in[4];
  const float* pa_b = (const float*)d_in[5];
  const float* cq_w = (const float*)d_in[6];
  const float* cq_b = (const float*)d_in[7];
  const float* ca_w = (const float*)d_in[8];
  // d_in[9] ca_b: softmax-invariant, dropped
  const float* rm_w = (const float*)d_in[10];
  const float* rm_b = (const float*)d_in[11];
  const float* ri_w = (const float*)d_in[12];
  // d_in[13] ri_b: softmax-invariant, dropped
  const float* ra_w = (const float*)d_in[14];
  // d_in[15] ra_b: softmax-invariant, dropped
  const float* wm_w = (const float*)d_in[16];
  const float* wm_b = (const float*)d_in[17];
  float* out = (float*)d_out;

  float* p = (float*)d_ws;
  float* q_pa_all = p; p += NSTEP * 32 * 1024;
  float* qc_all   = p; p += NSTEP * 32 * 1024;
  float* ri_wT    = p; p += 2048 * 1024;
  float* control  = p; p += 32 * 1024;
  float* mem0     = p; p += 32 * 1024;
  float* mem1     = p; p += 32 * 1024;
  float* cq       = p; p += 32 * 1024;
  float* mem_p    = p; p += 32 * 1024;
  float* h        = p; p += 32 * 2048;
  float* partial  = p; p += 16 * 32 * 512;
  float* readv    = p; p += 32 * 1024;

  init_control_kernel<<<32, 1024, 0, stream>>>(control_init, control);
  transpose_kernel<<<dim3(64, 32), dim3(32, 32), 0, stream>>>(ri_w, ri_wT);
  // q_pa_all[s] = question @ pa_w[s].T + pa_b[s]
  launch_gemm(question, 0, nullptr, 0, 2048, 0, pa_w, 2048, 1024L * 2048,
              pa_b, 1024, nullptr, 0, nullptr, q_pa_all, 32 * 1024, 1024, NSTEP, stream);
  hipMemcpyAsync(mem0, q_pa_all, 32 * 1024 * sizeof(float), hipMemcpyDeviceToDevice, stream);
  // qc_all[s] = q_pa_all[s] @ cq_w[:, D:].T   (hoisted out of the loop)
  launch_gemm(q_pa_all, 32 * 1024, nullptr, 0, 1024, 0, cq_w + 1024, 2048, 0,
              nullptr, 0, nullptr, 0, nullptr, qc_all, 32 * 1024, 1024, NSTEP, stream);

  float* mems[2] = {mem0, mem1};
  for (int s = 0; s < NSTEP; s++) {
    float* mo = mems[s & 1];
    float* mn = (s == NSTEP - 1) ? out : mems[(s + 1) & 1];
    // G1: cq = control @ cq_w[:, :D].T + qc_all[s] + cq_b
    launch_gemm(control, 0, nullptr, 0, 1024, 0, cq_w, 2048, 0,
                cq_b, 0, qc_all + (long)s * 32 * 1024, 0, nullptr, cq, 0, 1024, 1, stream);
    // G2: mem_p = memory @ rm_w.T + rm_b
    launch_gemm(mo, 0, nullptr, 0, 1024, 0, rm_w, 1024, 0,
                rm_b, 0, nullptr, 0, nullptr, mem_p, 0, 1024, 1, stream);
    // P2: context attention -> new control (in place for next step)
    ctrl_att_kernel<<<32, 1024, 0, stream>>>(cq, context, ca_w, control);
    // G3: h = (control * ra_w) @ ri_w  ==  X @ ri_wT.T
    launch_gemm(control, 0, nullptr, 0, 1024, 0, ri_wT, 1024, 0,
                nullptr, 0, nullptr, 0, ra_w, h, 0, 2048, 1, stream);
    // G4: r_att partials over j-chunks (deterministic, no atomics)
    ratt_kernel<<<dim3(32, 16), 512, 0, stream>>>(knowledge, mem_p, h, partial);
    // P5: softmax + read
    read_kernel<<<dim3(32, 32), 256, 0, stream>>>(partial, knowledge, readv);
    // G6: new_memory = read @ wm_w[:, :D].T + memory @ wm_w[:, D:].T + wm_b
    launch_gemm(readv, 0, mo, 0, 1024, 1024, wm_w, 2048, 0,
                wm_b, 0, nullptr, 0, nullptr, mn, 0, 1024, 1, stream);
  }
}

// Round 2
// 1713.484 us; speedup vs baseline: 1.2717x; 1.2717x over previous
//
#include <hip/hip_runtime.h>

// MAC network forward, restructured:
//  - inter2 GEMM (34 GMAC/step) algebraically collapsed via linearity of the
//    r_att contraction: r_att[b,k] = sum_j knowledge[b,j,k]*g[b,j],
//    g = mem_p * h[:, :D] + h[:, D:],  h = (new_control*ra_w) @ ri_w.
//  - q_pa part of control-unit GEMM hoisted out of the step loop (qc_all).
//  - ca_b / ra_b / ri_b are per-row constants under softmax -> dropped.
// All fp32.
//
// R2: two GEMM kernels.
//  - gemm32_kernel: R0 version (1 col x 32 b per wave, 64KB X tile) for the
//    small in-loop GEMMs. Reverted after R1's grid-halving regressed them.
//  - gemm_wide_kernel: streaming kernel for the 96MB pa_w (and qc) GEMMs.
//    R1's version spilled acc[64] to scratch (launch_bounds(256,4) capped
//    VGPRs at 128; counters: WRITE_SIZE 36MB vs 1.5MB output, VGPR=64).
//    Fix: launch_bounds(256,2) (256-VGPR budget, no spill; 2 blocks/CU via
//    64KB LDS anyway) + double-buffered X staging + W register prefetch so
//    W-load latency hides under the FMA loop.

#define NSTEP 12

struct GemmArgs {
  const float* X1; long x1g;   // [32, c1], per-group stride
  const float* X2; long x2g;   // [32, c2] or null (concat second half)
  int c1, c2;
  const float* W; int ldw; long wg;      // W[N, C] row-major (out = X @ W.T)
  const float* bias; long biasg;         // len N or null
  const float* addend; long addg;        // [32, N] or null
  const float* xscale;                   // len C or null (elementwise on X)
  float* out; long outg;                 // [32, N]
  int N;
};

// out[b,n] = sum_c X[b,c]*W[n,c] (+bias +addend). Block: 256 thr = 4 waves,
// one output column per wave, X tile (32 x 512) in LDS, ds_read_b128 inner.
__global__ __launch_bounds__(256) void gemm32_kernel(GemmArgs a) {
  __shared__ float xs[32 * 512];  // 64 KB
  const int g = blockIdx.y;
  const int C = a.c1 + a.c2;
  const float* X1 = a.X1 + (long)g * a.x1g;
  const float* X2 = a.X2 ? a.X2 + (long)g * a.x2g : nullptr;
  const float* W = a.W + (long)g * a.wg;
  const int wave = threadIdx.x >> 6;
  const int lane = threadIdx.x & 63;
  const int n = blockIdx.x * 4 + wave;
  const float* wrow = W + (long)n * a.ldw;
  float acc[32];
#pragma unroll
  for (int b = 0; b < 32; b++) acc[b] = 0.f;

  for (int c0 = 0; c0 < C; c0 += 512) {
    __syncthreads();  // protect previous chunk's reads
#pragma unroll
    for (int i = 0; i < 16; i++) {
      int idx = threadIdx.x + 256 * i;  // 0..4095 float4 slots
      int b = idx >> 7;                 // 128 float4 per row
      int c4 = idx & 127;
      int c = c0 + c4 * 4;              // global column
      float4 v;
      if (c < a.c1) v = *(const float4*)(X1 + (long)b * a.c1 + c);
      else          v = *(const float4*)(X2 + (long)b * a.c2 + (c - a.c1));
      if (a.xscale) {
        float4 s = *(const float4*)(a.xscale + c);
        v.x *= s.x; v.y *= s.y; v.z *= s.z; v.w *= s.w;
      }
      *(float4*)(xs + b * 512 + c4 * 4) = v;
    }
    __syncthreads();
#pragma unroll
    for (int i = 0; i < 2; i++) {
      int c = i * 256 + lane * 4;
      float4 wv = *(const float4*)(wrow + c0 + c);
#pragma unroll
      for (int b = 0; b < 32; b++) {
        float4 xv = *(const float4*)(xs + b * 512 + c);
        acc[b] += wv.x * xv.x + wv.y * xv.y + wv.z * xv.z + wv.w * xv.w;
      }
    }
  }
  float res = 0.f;
#pragma unroll
  for (int b = 0; b < 32; b++) {
    float v = acc[b];
#pragma unroll
    for (int off = 32; off; off >>= 1) v += __shfl_xor(v, off, 64);
    if (lane == b) res = v;
  }
  if (lane < 32) {
    float o = res;
    if (a.bias) o += a.bias[(long)g * a.biasg + n];
    if (a.addend) o += a.addend[(long)g * a.addg + (long)lane * a.N + n];
    a.out[(long)g * a.outg + (long)lane * a.N + n] = o;
  }
}

// Streaming thin-M GEMM for large W (pa, qc). No xscale support.
// Block: 256 thr = 4 waves, 8-col x 32-row output tile.
// Wave w: columns n0 + (w>>1)*4 .. +3, batch half (w&1)*16 .. +15.
// Double-buffered 32x256 X tile in LDS; W regs prefetched one chunk ahead.
// Per chunk per wave: 4 W float4 global, 16 xv b128 LDS reads, 64 FMA4.
__global__ __launch_bounds__(256, 2) void gemm_wide_kernel(GemmArgs a) {
  __shared__ float xs[2][32 * 256];  // 2 x 32 KB
  const int g = blockIdx.y;
  const int C = a.c1 + a.c2;
  const int nc = C >> 8;  // chunks of 256 columns (C % 256 == 0)
  const float* X1 = a.X1 + (long)g * a.x1g;
  const float* X2 = a.X2 ? a.X2 + (long)g * a.x2g : nullptr;
  const float* W = a.W + (long)g * a.wg;
  const int wave = threadIdx.x >> 6;
  const int lane = threadIdx.x & 63;
  const int n0 = blockIdx.x * 8 + (wave >> 1) * 4;
  const int bh = (wave & 1) * 16;
  const float* wrow = W + (long)n0 * a.ldw;
  const int cl = lane * 4;  // this lane's column slot within a chunk

  float acc[64];
#pragma unroll
  for (int v = 0; v < 64; v++) acc[v] = 0.f;

  // ---- prologue: stage chunk 0, load W chunk 0 ----
  {
    float4 xr[8];
#pragma unroll
    for (int r = 0; r < 8; r++) {
      int idx = threadIdx.x + 256 * r;
      int c = (idx & 63) * 4;
      if (c < a.c1) xr[r] = *(const float4*)(X1 + (long)(idx >> 6) * a.c1 + c);
      else          xr[r] = *(const float4*)(X2 + (long)(idx >> 6) * a.c2 + (c - a.c1));
    }
#pragma unroll
    for (int r = 0; r < 8; r++) {
      int idx = threadIdx.x + 256 * r;
      *(float4*)(&xs[0][idx * 4]) = xr[r];
    }
  }
  const float* wp0 = wrow + cl;
  float4 wc0 = *(const float4*)(wp0);
  float4 wc1 = *(const float4*)(wp0 + (long)a.ldw);
  float4 wc2 = *(const float4*)(wp0 + 2 * (long)a.ldw);
  float4 wc3 = *(const float4*)(wp0 + 3 * (long)a.ldw);
  __syncthreads();

  for (int i = 0; i < nc; i++) {
    const bool hn = (i + 1) < nc;
    const int c0n = (i + 1) << 8;
    float4 xr[8];
    float4 wn0, wn1, wn2, wn3;
    if (hn) {
      // issue next chunk's X + W loads early (latency hides under compute)
#pragma unroll
      for (int r = 0; r < 8; r++) {
        int idx = threadIdx.x + 256 * r;
        int c = c0n + (idx & 63) * 4;
        if (c < a.c1) xr[r] = *(const float4*)(X1 + (long)(idx >> 6) * a.c1 + c);
        else          xr[r] = *(const float4*)(X2 + (long)(idx >> 6) * a.c2 + (c - a.c1));
      }
      const float* wp = wrow + c0n + cl;
      wn0 = *(const float4*)(wp);
      wn1 = *(const float4*)(wp + (long)a.ldw);
      wn2 = *(const float4*)(wp + 2 * (long)a.ldw);
      wn3 = *(const float4*)(wp + 3 * (long)a.ldw);
    }
    // compute current chunk from xs[i&1] with wc0..wc3
    const float* xb = &xs[i & 1][0];
#pragma unroll
    for (int b = 0; b < 16; b++) {
      float4 xv = *(const float4*)(xb + (bh + b) * 256 + cl);
      acc[b * 4 + 0] += wc0.x * xv.x + wc0.y * xv.y + wc0.z * xv.z + wc0.w * xv.w;
      acc[b * 4 + 1] += wc1.x * xv.x + wc1.y * xv.y + wc1.z * xv.z + wc1.w * xv.w;
      acc[b * 4 + 2] += wc2.x * xv.x + wc2.y * xv.y + wc2.z * xv.z + wc2.w * xv.w;
      acc[b * 4 + 3] += wc3.x * xv.x + wc3.y * xv.y + wc3.z * xv.z + wc3.w * xv.w;
    }
    if (hn) {
      // write staged X to the other buffer; rotate W regs
#pragma unroll
      for (int r = 0; r < 8; r++) {
        int idx = threadIdx.x + 256 * r;
        *(float4*)(&xs[(i + 1) & 1][idx * 4]) = xr[r];
      }
      wc0 = wn0; wc1 = wn1; wc2 = wn2; wc3 = wn3;
    }
    __syncthreads();
  }

  // Butterfly cross-lane reduction: 63 shuffles. Final: lane l holds the full
  // sum for v = l in acc[0], v = b_local*4 + j.
#pragma unroll
  for (int o = 32; o; o >>= 1) {
    bool up = (lane & o) != 0;
#pragma unroll
    for (int i = 0; i < o; i++) {
      float keep = up ? acc[i + o] : acc[i];
      float send = up ? acc[i] : acc[i + o];
      acc[i] = keep + __shfl_xor(send, o, 64);
    }
  }
  const int bo = bh + (lane >> 2);
  const int nn = n0 + (lane & 3);
  float res = acc[0];
  if (a.bias) res += a.bias[(long)g * a.biasg + nn];
  if (a.addend) res += a.addend[(long)g * a.addg + (long)bo * a.N + nn];
  a.out[(long)g * a.outg + (long)bo * a.N + nn] = res;
}

__global__ __launch_bounds__(1024) void init_control_kernel(const float* ci, float* control) {
  control[blockIdx.x * 1024 + threadIdx.x] = ci[0];
}

// ri_w [1024, 2048] -> ri_wT [2048, 1024]
__global__ __launch_bounds__(1024) void transpose_kernel(const float* in, float* out) {
  __shared__ float t[32][33];
  int j0 = blockIdx.x * 32;
  int d0 = blockIdx.y * 32;
  int tx = threadIdx.x, ty = threadIdx.y;
  t[ty][tx] = in[(long)(d0 + ty) * 2048 + j0 + tx];
  __syncthreads();
  out[(long)(j0 + ty) * 1024 + d0 + tx] = t[tx][ty];
}

// control-unit attention: scores over context, softmax, new_control.
// One block (1024 thr) per batch row.
__global__ __launch_bounds__(1024) void ctrl_att_kernel(const float* cq, const float* context,
                                                        const float* ca_w, float* control) {
  int b = blockIdx.x;
  __shared__ float u[1024];
  __shared__ float sc[128];
  int tid = threadIdx.x;
  int wave = tid >> 6, lane = tid & 63;
  u[tid] = cq[b * 1024 + tid] * ca_w[tid];
  __syncthreads();
  const float* ctx = context + (long)b * 128 * 1024;
#pragma unroll
  for (int i = 0; i < 8; i++) {
    int s = wave * 8 + i;  // 16 waves x 8 = 128 scores
    float v = 0.f;
#pragma unroll
    for (int c = 0; c < 16; c++) v += u[c * 64 + lane] * ctx[(long)s * 1024 + c * 64 + lane];
#pragma unroll
    for (int off = 32; off; off >>= 1) v += __shfl_xor(v, off, 64);
    if (lane == 0) sc[s] = v;  // ca_b dropped (softmax-invariant)
  }
  __syncthreads();
  if (wave == 0) {
    float a0 = sc[lane], a1 = sc[lane + 64];
    float m = fmaxf(a0, a1);
#pragma unroll
    for (int off = 32; off; off >>= 1) m = fmaxf(m, __shfl_xor(m, off, 64));
    float e0 = expf(a0 - m), e1 = expf(a1 - m);
    float s2 = e0 + e1;
#pragma unroll
    for (int off = 32; off; off >>= 1) s2 += __shfl_xor(s2, off, 64);
    float inv = 1.f / s2;
    sc[lane] = e0 * inv;
    sc[lane + 64] = e1 * inv;
  }
  __syncthreads();
  float acc = 0.f;
  for (int s = 0; s < 128; s++) acc += sc[s] * ctx[(long)s * 1024 + tid];
  control[b * 1024 + tid] = acc;
}

// r_att partials: partial[jc][b][k] = sum_{j in chunk jc} g[b,j]*knowledge[b,j,k]
__global__ __launch_bounds__(512) void ratt_kernel(const float* knowledge, const float* mem_p,
                                                   const float* h, float* partial) {
  int b = blockIdx.x, jc = blockIdx.y;
  int j0 = jc * 64;
  __shared__ float gl[64];
  if (threadIdx.x < 64) {
    int j = j0 + threadIdx.x;
    gl[threadIdx.x] = mem_p[b * 1024 + j] * h[b * 2048 + j] + h[b * 2048 + 1024 + j];
  }
  __syncthreads();
  int k = threadIdx.x;  // 512 threads <-> K=512
  const float* kb = knowledge + ((long)b * 1024 + j0) * 512 + k;
  float acc = 0.f;
#pragma unroll 8
  for (int jj = 0; jj < 64; jj++) acc += gl[jj] * kb[(long)jj * 512];
  partial[((long)jc * 32 + b) * 512 + k] = acc;
}

// softmax(r_att) + read[b,d] = sum_k a[k]*knowledge[b,d,k]
// block (b, dg): 256 thr; softmax recomputed per block from partials.
__global__ __launch_bounds__(256) void read_kernel(const float* partial, const float* knowledge,
                                                   float* readv) {
  int b = blockIdx.x, dg = blockIdx.y;
  __shared__ float aw[512];
  __shared__ float red[4];
  int tid = threadIdx.x;
  int wave = tid >> 6, lane = tid & 63;
  int k0 = tid * 2;
  float r0 = 0.f, r1 = 0.f;
#pragma unroll
  for (int p = 0; p < 16; p++) {
    const float* pp = partial + ((long)p * 32 + b) * 512;
    r0 += pp[k0];
    r1 += pp[k0 + 1];
  }
  float m = fmaxf(r0, r1);
#pragma unroll
  for (int off = 32; off; off >>= 1) m = fmaxf(m, __shfl_xor(m, off, 64));
  if (lane == 0) red[wave] = m;
  __syncthreads();
  m = fmaxf(fmaxf(red[0], red[1]), fmaxf(red[2], red[3]));
  __syncthreads();  // all reads of red done before rewrite
  float e0 = expf(r0 - m), e1 = expf(r1 - m);
  float s2 = e0 + e1;
#pragma unroll
  for (int off = 32; off; off >>= 1) s2 += __shfl_xor(s2, off, 64);
  if (lane == 0) red[wave] = s2;
  __syncthreads();
  s2 = red[0] + red[1] + red[2] + red[3];
  float inv = 1.f / s2;
  aw[k0] = e0 * inv;
  aw[k0 + 1] = e1 * inv;
  __syncthreads();
  int d0 = dg * 32 + wave * 8;  // 4 waves x 8 d each
  float acc[8];
#pragma unroll
  for (int i = 0; i < 8; i++) acc[i] = 0.f;
  const float* kb = knowledge + ((long)b * 1024 + d0) * 512;
  for (int kc = 0; kc < 8; kc++) {
    int kk = kc * 64 + lane;
    float av = aw[kk];
#pragma unroll
    for (int dd = 0; dd < 8; dd++) acc[dd] += av * kb[(long)dd * 512 + kk];
  }
#pragma unroll
  for (int dd = 0; dd < 8; dd++) {
    float v = acc[dd];
#pragma unroll
    for (int off = 32; off; off >>= 1) v += __shfl_xor(v, off, 64);
    if (lane == dd) readv[b * 1024 + d0 + dd] = v;
  }
}

static inline void launch_gemm(const float* X1, long x1g, const float* X2, long x2g,
                               int c1, int c2, const float* W, int ldw, long wg,
                               const float* bias, long biasg,
                               const float* addend, long addg,
                               const float* xscale, float* out, long outg, int N, int G,
                               hipStream_t stream) {
  GemmArgs a{X1, x1g, X2, x2g, c1, c2, W, ldw, wg, bias, biasg, addend, addg, xscale, out, outg, N};
  gemm32_kernel<<<dim3(N / 4, G), 256, 0, stream>>>(a);
}

static inline void launch_gemm_wide(const float* X1, long x1g, int c1,
                                    const float* W, int ldw, long wg,
                                    const float* bias, long biasg,
                                    float* out, long outg, int N, int G,
                                    hipStream_t stream) {
  GemmArgs a{X1, x1g, nullptr, 0, c1, 0, W, ldw, wg, bias, biasg,
             nullptr, 0, nullptr, out, outg, N};
  gemm_wide_kernel<<<dim3(N / 8, G), 256, 0, stream>>>(a);
}

extern "C" void kernel_launch(void* const* d_in, const int* in_sizes, int n_in,
                              void* d_out, int out_size, void* d_ws, size_t ws_size,
                              hipStream_t stream) {
  const float* context      = (const float*)d_in[0];
  const float* question     = (const float*)d_in[1];
  const float* knowledge    = (const float*)d_in[2];
  const float* control_init = (const float*)d_in[3];
  const float* pa_w = (const float*)d_in[4];
  const float* pa_b = (const float*)d_in[5];
  const float* cq_w = (const float*)d_in[6];
  const float* cq_b = (const float*)d_in[7];
  const float* ca_w = (const float*)d_in[8];
  // d_in[9] ca_b: softmax-invariant, dropped
  const float* rm_w = (const float*)d_in[10];
  const float* rm_b = (const float*)d_in[11];
  const float* ri_w = (const float*)d_in[12];
  // d_in[13] ri_b: softmax-invariant, dropped
  const float* ra_w = (const float*)d_in[14];
  // d_in[15] ra_b: softmax-invariant, dropped
  const float* wm_w = (const float*)d_in[16];
  const float* wm_b = (const float*)d_in[17];
  float* out = (float*)d_out;

  float* p = (float*)d_ws;
  float* q_pa_all = p; p += NSTEP * 32 * 1024;
  float* qc_all   = p; p += NSTEP * 32 * 1024;
  float* ri_wT    = p; p += 2048 * 1024;
  float* control  = p; p += 32 * 1024;
  float* mem0     = p; p += 32 * 1024;
  float* mem1     = p; p += 32 * 1024;
  float* cq       = p; p += 32 * 1024;
  float* mem_p    = p; p += 32 * 1024;
  float* h        = p; p += 32 * 2048;
  float* partial  = p; p += 16 * 32 * 512;
  float* readv    = p; p += 32 * 1024;

  init_control_kernel<<<32, 1024, 0, stream>>>(control_init, control);
  transpose_kernel<<<dim3(64, 32), dim3(32, 32), 0, stream>>>(ri_w, ri_wT);
  // q_pa_all[s] = question @ pa_w[s].T + pa_b[s]   (96 MB W stream)
  launch_gemm_wide(question, 0, 2048, pa_w, 2048, 1024L * 2048,
                   pa_b, 1024, q_pa_all, 32 * 1024, 1024, NSTEP, stream);
  hipMemcpyAsync(mem0, q_pa_all, 32 * 1024 * sizeof(float), hipMemcpyDeviceToDevice, stream);
  // qc_all[s] = q_pa_all[s] @ cq_w[:, D:].T   (hoisted out of the loop)
  launch_gemm_wide(q_pa_all, 32 * 1024, 1024, cq_w + 1024, 2048, 0,
                   nullptr, 0, qc_all, 32 * 1024, 1024, NSTEP, stream);

  float* mems[2] = {mem0, mem1};
  for (int s = 0; s < NSTEP; s++) {
    float* mo = mems[s & 1];
    float* mn = (s == NSTEP - 1) ? out : mems[(s + 1) & 1];
    // G1: cq = control @ cq_w[:, :D].T + qc_all[s] + cq_b
    launch_gemm(control, 0, nullptr, 0, 1024, 0, cq_w, 2048, 0,
                cq_b, 0, qc_all + (long)s * 32 * 1024, 0, nullptr, cq, 0, 1024, 1, stream);
    // G2: mem_p = memory @ rm_w.T + rm_b
    launch_gemm(mo, 0, nullptr, 0, 1024, 0, rm_w, 1024, 0,
                rm_b, 0, nullptr, 0, nullptr, mem_p, 0, 1024, 1, stream);
    // P2: context attention -> new control (in place for next step)
    ctrl_att_kernel<<<32, 1024, 0, stream>>>(cq, context, ca_w, control);
    // G3: h = (control * ra_w) @ ri_w  ==  X @ ri_wT.T
    launch_gemm(control, 0, nullptr, 0, 1024, 0, ri_wT, 1024, 0,
                nullptr, 0, nullptr, 0, ra_w, h, 0, 2048, 1, stream);
    // G4: r_att partials over j-chunks (deterministic, no atomics)
    ratt_kernel<<<dim3(32, 16), 512, 0, stream>>>(knowledge, mem_p, h, partial);
    // P5: softmax + read
    read_kernel<<<dim3(32, 32), 256, 0, stream>>>(partial, knowledge, readv);
    // G6: new_memory = read @ wm_w[:, :D].T + memory @ wm_w[:, D:].T + wm_b
    launch_gemm(readv, 0, mo, 0, 1024, 1024, wm_w, 2048, 0,
                wm_b, 0, nullptr, 0, nullptr, mn, 0, 1024, 1, stream);
  }
}

// Round 3
// 1560.424 us; speedup vs baseline: 1.3964x; 1.0981x over previous
//
#include <hip/hip_runtime.h>

// MAC network forward, restructured:
//  - inter2 GEMM (34 GMAC/step) algebraically collapsed via linearity of the
//    r_att contraction: r_att[b,k] = sum_j knowledge[b,j,k]*g[b,j],
//    g = mem_p * h[:, :D] + h[:, D:],  h = (new_control*ra_w) @ ri_w.
//  - q_pa part of control-unit GEMM hoisted out of the step loop (qc_all).
//  - ca_b / ra_b / ri_b are per-row constants under softmax -> dropped.
// All fp32.
//
// R3: gemm_wide_kernel staging rebuilt on __builtin_amdgcn_global_load_lds.
// R2 spilled ~250MB/dispatch to scratch because the float4 xr[8] staging
// array (32 VGPRs) was live across the FMA loop and the allocator stopped at
// 128 VGPRs. global_load_lds removes the register round-trip entirely:
// per (wave,r) the X row is wave-uniform and the LDS dest is linear
// base+lane*16 -- exactly the HW pattern. Peak pressure ~110 VGPRs -> no
// spill. Double-buffered LDS; __syncthreads() drains vmcnt each chunk.

#define NSTEP 12

struct GemmArgs {
  const float* X1; long x1g;   // [32, c1], per-group stride
  const float* X2; long x2g;   // [32, c2] or null (concat second half)
  int c1, c2;
  const float* W; int ldw; long wg;      // W[N, C] row-major (out = X @ W.T)
  const float* bias; long biasg;         // len N or null
  const float* addend; long addg;        // [32, N] or null
  const float* xscale;                   // len C or null (elementwise on X)
  float* out; long outg;                 // [32, N]
  int N;
};

// out[b,n] = sum_c X[b,c]*W[n,c] (+bias +addend). Block: 256 thr = 4 waves,
// one output column per wave, X tile (32 x 512) in LDS, ds_read_b128 inner.
__global__ __launch_bounds__(256) void gemm32_kernel(GemmArgs a) {
  __shared__ float xs[32 * 512];  // 64 KB
  const int g = blockIdx.y;
  const int C = a.c1 + a.c2;
  const float* X1 = a.X1 + (long)g * a.x1g;
  const float* X2 = a.X2 ? a.X2 + (long)g * a.x2g : nullptr;
  const float* W = a.W + (long)g * a.wg;
  const int wave = threadIdx.x >> 6;
  const int lane = threadIdx.x & 63;
  const int n = blockIdx.x * 4 + wave;
  const float* wrow = W + (long)n * a.ldw;
  float acc[32];
#pragma unroll
  for (int b = 0; b < 32; b++) acc[b] = 0.f;

  for (int c0 = 0; c0 < C; c0 += 512) {
    __syncthreads();  // protect previous chunk's reads
#pragma unroll
    for (int i = 0; i < 16; i++) {
      int idx = threadIdx.x + 256 * i;  // 0..4095 float4 slots
      int b = idx >> 7;                 // 128 float4 per row
      int c4 = idx & 127;
      int c = c0 + c4 * 4;              // global column
      float4 v;
      if (c < a.c1) v = *(const float4*)(X1 + (long)b * a.c1 + c);
      else          v = *(const float4*)(X2 + (long)b * a.c2 + (c - a.c1));
      if (a.xscale) {
        float4 s = *(const float4*)(a.xscale + c);
        v.x *= s.x; v.y *= s.y; v.z *= s.z; v.w *= s.w;
      }
      *(float4*)(xs + b * 512 + c4 * 4) = v;
    }
    __syncthreads();
#pragma unroll
    for (int i = 0; i < 2; i++) {
      int c = i * 256 + lane * 4;
      float4 wv = *(const float4*)(wrow + c0 + c);
#pragma unroll
      for (int b = 0; b < 32; b++) {
        float4 xv = *(const float4*)(xs + b * 512 + c);
        acc[b] += wv.x * xv.x + wv.y * xv.y + wv.z * xv.z + wv.w * xv.w;
      }
    }
  }
  float res = 0.f;
#pragma unroll
  for (int b = 0; b < 32; b++) {
    float v = acc[b];
#pragma unroll
    for (int off = 32; off; off >>= 1) v += __shfl_xor(v, off, 64);
    if (lane == b) res = v;
  }
  if (lane < 32) {
    float o = res;
    if (a.bias) o += a.bias[(long)g * a.biasg + n];
    if (a.addend) o += a.addend[(long)g * a.addg + (long)lane * a.N + n];
    a.out[(long)g * a.outg + (long)lane * a.N + n] = o;
  }
}

__device__ __forceinline__ void gload_lds16(const float* g, float* l) {
  __builtin_amdgcn_global_load_lds(
      (const __attribute__((address_space(1))) void*)g,
      (__attribute__((address_space(3))) void*)l, 16, 0, 0);
}

// Streaming thin-M GEMM for large W (pa, qc). X1-only (no concat/xscale).
// Block: 256 thr = 4 waves, 8-col x 32-row output tile.
// Wave w: columns n0 + (w>>1)*4 .. +3, batch half (w&1)*16 .. +15.
// X staged via global_load_lds (no VGPR round-trip), double-buffered 32KB
// chunks; W regs prefetched one chunk ahead (latency hides under FMA loop).
// Per chunk per wave: 4 W float4 global, 8 lds-DMA, 16 xv b128, 64 FMA4.
__global__ __launch_bounds__(256, 2) void gemm_wide_kernel(GemmArgs a) {
  __shared__ float xs[2][32 * 256];  // 2 x 32 KB
  const int g = blockIdx.y;
  const int C = a.c1;
  const int nc = C >> 8;  // chunks of 256 columns (C % 256 == 0)
  const float* X1 = a.X1 + (long)g * a.x1g;
  const float* W = a.W + (long)g * a.wg;
  const int wave = threadIdx.x >> 6;
  const int lane = threadIdx.x & 63;
  const int n0 = blockIdx.x * 8 + (wave >> 1) * 4;
  const int bh = (wave & 1) * 16;
  const float* wrow = W + (long)n0 * a.ldw;
  const int cl = lane * 4;  // this lane's column slot within a chunk

  float acc[64];
#pragma unroll
  for (int v = 0; v < 64; v++) acc[v] = 0.f;

  // stage one 32x256 chunk into xs[buf] via direct global->LDS DMA.
  // thread t, call r: float4 slot idx = t + 256r; row b = idx>>6 is
  // wave-uniform; LDS dest = linear base + lane*16 (HW-required layout).
  auto stage = [&](int buf, int c0) {
#pragma unroll
    for (int r = 0; r < 8; r++) {
      int idx = threadIdx.x + 256 * r;
      int b = idx >> 6;
      gload_lds16(X1 + (long)b * C + c0 + (idx & 63) * 4, &xs[buf][idx * 4]);
    }
  };

  // ---- prologue: stage chunk 0, load W chunk 0 ----
  stage(0, 0);
  const float* wp0 = wrow + cl;
  float4 wc0 = *(const float4*)(wp0);
  float4 wc1 = *(const float4*)(wp0 + (long)a.ldw);
  float4 wc2 = *(const float4*)(wp0 + 2 * (long)a.ldw);
  float4 wc3 = *(const float4*)(wp0 + 3 * (long)a.ldw);
  __syncthreads();  // drains vmcnt -> chunk 0 resident

  for (int i = 0; i < nc; i++) {
    const bool hn = (i + 1) < nc;
    float4 wn0, wn1, wn2, wn3;
    if (hn) {
      // issue next chunk's X DMA + W loads early; they drain at the barrier
      const int c0n = (i + 1) << 8;
      stage((i + 1) & 1, c0n);
      const float* wp = wrow + c0n + cl;
      wn0 = *(const float4*)(wp);
      wn1 = *(const float4*)(wp + (long)a.ldw);
      wn2 = *(const float4*)(wp + 2 * (long)a.ldw);
      wn3 = *(const float4*)(wp + 3 * (long)a.ldw);
    }
    // compute current chunk from xs[i&1] with wc0..wc3
    const float* xb = &xs[i & 1][0];
#pragma unroll
    for (int b = 0; b < 16; b++) {
      float4 xv = *(const float4*)(xb + (bh + b) * 256 + cl);
      acc[b * 4 + 0] += wc0.x * xv.x + wc0.y * xv.y + wc0.z * xv.z + wc0.w * xv.w;
      acc[b * 4 + 1] += wc1.x * xv.x + wc1.y * xv.y + wc1.z * xv.z + wc1.w * xv.w;
      acc[b * 4 + 2] += wc2.x * xv.x + wc2.y * xv.y + wc2.z * xv.z + wc2.w * xv.w;
      acc[b * 4 + 3] += wc3.x * xv.x + wc3.y * xv.y + wc3.z * xv.z + wc3.w * xv.w;
    }
    if (hn) { wc0 = wn0; wc1 = wn1; wc2 = wn2; wc3 = wn3; }
    __syncthreads();  // next chunk's DMA drained; buffers swap
  }

  // Butterfly cross-lane reduction: 63 shuffles. Final: lane l holds the full
  // sum for v = l in acc[0], v = b_local*4 + j.
#pragma unroll
  for (int o = 32; o; o >>= 1) {
    bool up = (lane & o) != 0;
#pragma unroll
    for (int i = 0; i < o; i++) {
      float keep = up ? acc[i + o] : acc[i];
      float send = up ? acc[i] : acc[i + o];
      acc[i] = keep + __shfl_xor(send, o, 64);
    }
  }
  const int bo = bh + (lane >> 2);
  const int nn = n0 + (lane & 3);
  float res = acc[0];
  if (a.bias) res += a.bias[(long)g * a.biasg + nn];
  if (a.addend) res += a.addend[(long)g * a.addg + (long)bo * a.N + nn];
  a.out[(long)g * a.outg + (long)bo * a.N + nn] = res;
}

__global__ __launch_bounds__(1024) void init_control_kernel(const float* ci, float* control) {
  control[blockIdx.x * 1024 + threadIdx.x] = ci[0];
}

// ri_w [1024, 2048] -> ri_wT [2048, 1024]
__global__ __launch_bounds__(1024) void transpose_kernel(const float* in, float* out) {
  __shared__ float t[32][33];
  int j0 = blockIdx.x * 32;
  int d0 = blockIdx.y * 32;
  int tx = threadIdx.x, ty = threadIdx.y;
  t[ty][tx] = in[(long)(d0 + ty) * 2048 + j0 + tx];
  __syncthreads();
  out[(long)(j0 + ty) * 1024 + d0 + tx] = t[tx][ty];
}

// control-unit attention: scores over context, softmax, new_control.
// One block (1024 thr) per batch row.
__global__ __launch_bounds__(1024) void ctrl_att_kernel(const float* cq, const float* context,
                                                        const float* ca_w, float* control) {
  int b = blockIdx.x;
  __shared__ float u[1024];
  __shared__ float sc[128];
  int tid = threadIdx.x;
  int wave = tid >> 6, lane = tid & 63;
  u[tid] = cq[b * 1024 + tid] * ca_w[tid];
  __syncthreads();
  const float* ctx = context + (long)b * 128 * 1024;
#pragma unroll
  for (int i = 0; i < 8; i++) {
    int s = wave * 8 + i;  // 16 waves x 8 = 128 scores
    float v = 0.f;
#pragma unroll
    for (int c = 0; c < 16; c++) v += u[c * 64 + lane] * ctx[(long)s * 1024 + c * 64 + lane];
#pragma unroll
    for (int off = 32; off; off >>= 1) v += __shfl_xor(v, off, 64);
    if (lane == 0) sc[s] = v;  // ca_b dropped (softmax-invariant)
  }
  __syncthreads();
  if (wave == 0) {
    float a0 = sc[lane], a1 = sc[lane + 64];
    float m = fmaxf(a0, a1);
#pragma unroll
    for (int off = 32; off; off >>= 1) m = fmaxf(m, __shfl_xor(m, off, 64));
    float e0 = expf(a0 - m), e1 = expf(a1 - m);
    float s2 = e0 + e1;
#pragma unroll
    for (int off = 32; off; off >>= 1) s2 += __shfl_xor(s2, off, 64);
    float inv = 1.f / s2;
    sc[lane] = e0 * inv;
    sc[lane + 64] = e1 * inv;
  }
  __syncthreads();
  float acc = 0.f;
  for (int s = 0; s < 128; s++) acc += sc[s] * ctx[(long)s * 1024 + tid];
  control[b * 1024 + tid] = acc;
}

// r_att partials: partial[jc][b][k] = sum_{j in chunk jc} g[b,j]*knowledge[b,j,k]
__global__ __launch_bounds__(512) void ratt_kernel(const float* knowledge, const float* mem_p,
                                                   const float* h, float* partial) {
  int b = blockIdx.x, jc = blockIdx.y;
  int j0 = jc * 64;
  __shared__ float gl[64];
  if (threadIdx.x < 64) {
    int j = j0 + threadIdx.x;
    gl[threadIdx.x] = mem_p[b * 1024 + j] * h[b * 2048 + j] + h[b * 2048 + 1024 + j];
  }
  __syncthreads();
  int k = threadIdx.x;  // 512 threads <-> K=512
  const float* kb = knowledge + ((long)b * 1024 + j0) * 512 + k;
  float acc = 0.f;
#pragma unroll 8
  for (int jj = 0; jj < 64; jj++) acc += gl[jj] * kb[(long)jj * 512];
  partial[((long)jc * 32 + b) * 512 + k] = acc;
}

// softmax(r_att) + read[b,d] = sum_k a[k]*knowledge[b,d,k]
// block (b, dg): 256 thr; softmax recomputed per block from partials.
__global__ __launch_bounds__(256) void read_kernel(const float* partial, const float* knowledge,
                                                   float* readv) {
  int b = blockIdx.x, dg = blockIdx.y;
  __shared__ float aw[512];
  __shared__ float red[4];
  int tid = threadIdx.x;
  int wave = tid >> 6, lane = tid & 63;
  int k0 = tid * 2;
  float r0 = 0.f, r1 = 0.f;
#pragma unroll
  for (int p = 0; p < 16; p++) {
    const float* pp = partial + ((long)p * 32 + b) * 512;
    r0 += pp[k0];
    r1 += pp[k0 + 1];
  }
  float m = fmaxf(r0, r1);
#pragma unroll
  for (int off = 32; off; off >>= 1) m = fmaxf(m, __shfl_xor(m, off, 64));
  if (lane == 0) red[wave] = m;
  __syncthreads();
  m = fmaxf(fmaxf(red[0], red[1]), fmaxf(red[2], red[3]));
  __syncthreads();  // all reads of red done before rewrite
  float e0 = expf(r0 - m), e1 = expf(r1 - m);
  float s2 = e0 + e1;
#pragma unroll
  for (int off = 32; off; off >>= 1) s2 += __shfl_xor(s2, off, 64);
  if (lane == 0) red[wave] = s2;
  __syncthreads();
  s2 = red[0] + red[1] + red[2] + red[3];
  float inv = 1.f / s2;
  aw[k0] = e0 * inv;
  aw[k0 + 1] = e1 * inv;
  __syncthreads();
  int d0 = dg * 32 + wave * 8;  // 4 waves x 8 d each
  float acc[8];
#pragma unroll
  for (int i = 0; i < 8; i++) acc[i] = 0.f;
  const float* kb = knowledge + ((long)b * 1024 + d0) * 512;
  for (int kc = 0; kc < 8; kc++) {
    int kk = kc * 64 + lane;
    float av = aw[kk];
#pragma unroll
    for (int dd = 0; dd < 8; dd++) acc[dd] += av * kb[(long)dd * 512 + kk];
  }
#pragma unroll
  for (int dd = 0; dd < 8; dd++) {
    float v = acc[dd];
#pragma unroll
    for (int off = 32; off; off >>= 1) v += __shfl_xor(v, off, 64);
    if (lane == dd) readv[b * 1024 + d0 + dd] = v;
  }
}

static inline void launch_gemm(const float* X1, long x1g, const float* X2, long x2g,
                               int c1, int c2, const float* W, int ldw, long wg,
                               const float* bias, long biasg,
                               const float* addend, long addg,
                               const float* xscale, float* out, long outg, int N, int G,
                               hipStream_t stream) {
  GemmArgs a{X1, x1g, X2, x2g, c1, c2, W, ldw, wg, bias, biasg, addend, addg, xscale, out, outg, N};
  gemm32_kernel<<<dim3(N / 4, G), 256, 0, stream>>>(a);
}

static inline void launch_gemm_wide(const float* X1, long x1g, int c1,
                                    const float* W, int ldw, long wg,
                                    const float* bias, long biasg,
                                    float* out, long outg, int N, int G,
                                    hipStream_t stream) {
  GemmArgs a{X1, x1g, nullptr, 0, c1, 0, W, ldw, wg, bias, biasg,
             nullptr, 0, nullptr, out, outg, N};
  gemm_wide_kernel<<<dim3(N / 8, G), 256, 0, stream>>>(a);
}

extern "C" void kernel_launch(void* const* d_in, const int* in_sizes, int n_in,
                              void* d_out, int out_size, void* d_ws, size_t ws_size,
                              hipStream_t stream) {
  const float* context      = (const float*)d_in[0];
  const float* question     = (const float*)d_in[1];
  const float* knowledge    = (const float*)d_in[2];
  const float* control_init = (const float*)d_in[3];
  const float* pa_w = (const float*)d_in[4];
  const float* pa_b = (const float*)d_in[5];
  const float* cq_w = (const float*)d_in[6];
  const float* cq_b = (const float*)d_in[7];
  const float* ca_w = (const float*)d_in[8];
  // d_in[9] ca_b: softmax-invariant, dropped
  const float* rm_w = (const float*)d_in[10];
  const float* rm_b = (const float*)d_in[11];
  const float* ri_w = (const float*)d_in[12];
  // d_in[13] ri_b: softmax-invariant, dropped
  const float* ra_w = (const float*)d_in[14];
  // d_in[15] ra_b: softmax-invariant, dropped
  const float* wm_w = (const float*)d_in[16];
  const float* wm_b = (const float*)d_in[17];
  float* out = (float*)d_out;

  float* p = (float*)d_ws;
  float* q_pa_all = p; p += NSTEP * 32 * 1024;
  float* qc_all   = p; p += NSTEP * 32 * 1024;
  float* ri_wT    = p; p += 2048 * 1024;
  float* control  = p; p += 32 * 1024;
  float* mem0     = p; p += 32 * 1024;
  float* mem1     = p; p += 32 * 1024;
  float* cq       = p; p += 32 * 1024;
  float* mem_p    = p; p += 32 * 1024;
  float* h        = p; p += 32 * 2048;
  float* partial  = p; p += 16 * 32 * 512;
  float* readv    = p; p += 32 * 1024;

  init_control_kernel<<<32, 1024, 0, stream>>>(control_init, control);
  transpose_kernel<<<dim3(64, 32), dim3(32, 32), 0, stream>>>(ri_w, ri_wT);
  // q_pa_all[s] = question @ pa_w[s].T + pa_b[s]   (96 MB W stream)
  launch_gemm_wide(question, 0, 2048, pa_w, 2048, 1024L * 2048,
                   pa_b, 1024, q_pa_all, 32 * 1024, 1024, NSTEP, stream);
  hipMemcpyAsync(mem0, q_pa_all, 32 * 1024 * sizeof(float), hipMemcpyDeviceToDevice, stream);
  // qc_all[s] = q_pa_all[s] @ cq_w[:, D:].T   (hoisted out of the loop)
  launch_gemm_wide(q_pa_all, 32 * 1024, 1024, cq_w + 1024, 2048, 0,
                   nullptr, 0, qc_all, 32 * 1024, 1024, NSTEP, stream);

  float* mems[2] = {mem0, mem1};
  for (int s = 0; s < NSTEP; s++) {
    float* mo = mems[s & 1];
    float* mn = (s == NSTEP - 1) ? out : mems[(s + 1) & 1];
    // G1: cq = control @ cq_w[:, :D].T + qc_all[s] + cq_b
    launch_gemm(control, 0, nullptr, 0, 1024, 0, cq_w, 2048, 0,
                cq_b, 0, qc_all + (long)s * 32 * 1024, 0, nullptr, cq, 0, 1024, 1, stream);
    // G2: mem_p = memory @ rm_w.T + rm_b
    launch_gemm(mo, 0, nullptr, 0, 1024, 0, rm_w, 1024, 0,
                rm_b, 0, nullptr, 0, nullptr, mem_p, 0, 1024, 1, stream);
    // P2: context attention -> new control (in place for next step)
    ctrl_att_kernel<<<32, 1024, 0, stream>>>(cq, context, ca_w, control);
    // G3: h = (control * ra_w) @ ri_w  ==  X @ ri_wT.T
    launch_gemm(control, 0, nullptr, 0, 1024, 0, ri_wT, 1024, 0,
                nullptr, 0, nullptr, 0, ra_w, h, 0, 2048, 1, stream);
    // G4: r_att partials over j-chunks (deterministic, no atomics)
    ratt_kernel<<<dim3(32, 16), 512, 0, stream>>>(knowledge, mem_p, h, partial);
    // P5: softmax + read
    read_kernel<<<dim3(32, 32), 256, 0, stream>>>(partial, knowledge, readv);
    // G6: new_memory = read @ wm_w[:, :D].T + memory @ wm_w[:, D:].T + wm_b
    launch_gemm(readv, 0, mo, 0, 1024, 1024, wm_w, 2048, 0,
                wm_b, 0, nullptr, 0, nullptr, mn, 0, 1024, 1, stream);
  }
}